// Round 4
// baseline (451.582 us; speedup 1.0000x reference)
//
#include <hip/hip_runtime.h>

typedef unsigned short u16;
typedef __attribute__((ext_vector_type(8))) __bf16 bf16x8;
typedef __attribute__((ext_vector_type(4))) float f32x4;
typedef __attribute__((ext_vector_type(8))) unsigned short us8v;

__device__ __forceinline__ u16 f2bf(float x){
  union { float f; unsigned u; } v; v.f = x;
  unsigned r = v.u + 0x7fffu + ((v.u >> 16) & 1u);
  return (u16)(r >> 16);
}
__device__ __forceinline__ float bf2f(u16 h){
  union { unsigned u; float f; } v; v.u = ((unsigned)h) << 16;
  return v.f;
}
// async global->LDS, 16B per lane. lds ptr must be wave-uniform; HW writes base + lane*16.
__device__ __forceinline__ void gld16(const void* g, void* l){
  __builtin_amdgcn_global_load_lds((const __attribute__((address_space(1))) unsigned int*)g,
                                   (__attribute__((address_space(3))) unsigned int*)l, 16, 0, 0);
}

// ---------- transpose + fp32->bf16 convert: S[R][C] -> D[C][R] ----------
__global__ __launch_bounds__(256) void tr_cvt(const float* __restrict__ S, u16* __restrict__ D,
                                              int R, int C){
  __shared__ float t[32][33];
  int c0 = blockIdx.x*32, r0 = blockIdx.y*32;
  int tx = threadIdx.x, ty = threadIdx.y;
  #pragma unroll
  for (int j=0;j<32;j+=8) t[ty+j][tx] = S[(size_t)(r0+ty+j)*C + (c0+tx)];
  __syncthreads();
  #pragma unroll
  for (int j=0;j<32;j+=8) D[(size_t)(c0+ty+j)*R + (r0+tx)] = f2bf(t[tx][ty+j]);
}

// ---------- Wup transpose with G/U interleave: WupT row (pair*32+lo) = Wup col
//            (lo<16 ? pair*16+lo : 4096 + pair*16 + lo-16). S is [1024][8192]. ----------
__global__ __launch_bounds__(256) void tr_cvt_up(const float* __restrict__ S, u16* __restrict__ D){
  __shared__ float t[32][33];
  int c0 = blockIdx.x*32, r0 = blockIdx.y*32;
  int tx = threadIdx.x, ty = threadIdx.y;
  #pragma unroll
  for (int j=0;j<32;j+=8) t[ty+j][tx] = S[(size_t)(r0+ty+j)*8192 + (c0+tx)];
  __syncthreads();
  #pragma unroll
  for (int j=0;j<32;j+=8){
    int c = c0 + ty + j;
    int rdst = (c < 4096) ? ((c>>4)*32 + (c&15)) : (((c-4096)>>4)*32 + 16 + (c&15));
    D[(size_t)rdst*1024 + (r0+tx)] = f2bf(t[tx][ty+j]);
  }
}

// ---------- layernorm (+optional residual X), fp32 in -> bf16 out. D=1024, 256 thr ----------
__global__ __launch_bounds__(256) void ln_kernel(const float* __restrict__ Q, const float* __restrict__ X,
    const float* __restrict__ g, const float* __restrict__ b, u16* __restrict__ O){
  int row = blockIdx.x, tid = threadIdx.x;
  const float4 x = ((const float4*)(Q + (size_t)row*1024))[tid];
  float s = x.x + x.y + x.z + x.w;
  float sq = x.x*x.x + x.y*x.y + x.z*x.z + x.w*x.w;
  #pragma unroll
  for (int o=32;o>0;o>>=1){ s += __shfl_xor(s, o); sq += __shfl_xor(sq, o); }
  __shared__ float ss[4], ssq[4];
  int wid = tid>>6;
  if ((tid&63)==0){ ss[wid]=s; ssq[wid]=sq; }
  __syncthreads();
  s = ss[0]+ss[1]+ss[2]+ss[3]; sq = ssq[0]+ssq[1]+ssq[2]+ssq[3];
  float mu = s*(1.0f/1024.0f);
  float var = sq*(1.0f/1024.0f) - mu*mu;
  float rstd = rsqrtf(var + 1e-5f);
  float4 xx = make_float4(0.f,0.f,0.f,0.f);
  if (X) xx = ((const float4*)(X + (size_t)row*1024))[tid];
  float4 gv = ((const float4*)g)[tid];
  float4 bv = ((const float4*)b)[tid];
  ushort4 o;
  o.x = f2bf((x.x-mu)*rstd*gv.x + bv.x + xx.x);
  o.y = f2bf((x.y-mu)*rstd*gv.y + bv.y + xx.y);
  o.z = f2bf((x.z-mu)*rstd*gv.z + bv.z + xx.z);
  o.w = f2bf((x.w-mu)*rstd*gv.w + bv.w + xx.w);
  ((ushort4*)(O + (size_t)row*1024))[tid] = o;
}

// ---------- ln2: Qint = Q_in + softplus(dt)*(P0+P1); Qn2 = LN(Qint)*g+b ----------
__global__ __launch_bounds__(256) void ln2_kernel(const float* __restrict__ P,
    const float* __restrict__ Qin, const float* __restrict__ dtp,
    const float* __restrict__ g, const float* __restrict__ b,
    float* __restrict__ Qint, u16* __restrict__ Qn2){
  int row = blockIdx.x, tid = threadIdx.x;
  float sp = log1pf(__expf(dtp[0]));
  size_t off = (size_t)row*1024;
  float4 p0 = ((const float4*)(P + off))[tid];
  float4 p1 = ((const float4*)(P + 4194304 + off))[tid];
  float4 q  = ((const float4*)(Qin + off))[tid];
  float4 x;
  x.x = q.x + sp*(p0.x+p1.x); x.y = q.y + sp*(p0.y+p1.y);
  x.z = q.z + sp*(p0.z+p1.z); x.w = q.w + sp*(p0.w+p1.w);
  ((float4*)(Qint + off))[tid] = x;
  float s = x.x + x.y + x.z + x.w;
  float sq = x.x*x.x + x.y*x.y + x.z*x.z + x.w*x.w;
  #pragma unroll
  for (int o=32;o>0;o>>=1){ s += __shfl_xor(s, o); sq += __shfl_xor(sq, o); }
  __shared__ float ss[4], ssq[4];
  int wid = tid>>6;
  if ((tid&63)==0){ ss[wid]=s; ssq[wid]=sq; }
  __syncthreads();
  s = ss[0]+ss[1]+ss[2]+ss[3]; sq = ssq[0]+ssq[1]+ssq[2]+ssq[3];
  float mu = s*(1.0f/1024.0f);
  float var = sq*(1.0f/1024.0f) - mu*mu;
  float rstd = rsqrtf(var + 1e-5f);
  float4 gv = ((const float4*)g)[tid];
  float4 bv = ((const float4*)b)[tid];
  ushort4 o;
  o.x = f2bf((x.x-mu)*rstd*gv.x + bv.x);
  o.y = f2bf((x.y-mu)*rstd*gv.y + bv.y);
  o.z = f2bf((x.z-mu)*rstd*gv.z + bv.z);
  o.w = f2bf((x.w-mu)*rstd*gv.w + bv.w);
  ((ushort4*)(Qn2 + off))[tid] = o;
}

// ---------- generic bf16 GEMM, A[M][K] @ Bt[Nc][K]^T, m97 structure ----------
// EPI 5 = fused QKV: col<1024 -> phi->PhiQ, <2048 -> phi->PhiK, else Vt (Op = PhiQ base)
template<int EPI>
__global__ __launch_bounds__(256, 3) void gemm_bt(
    const u16* __restrict__ A, const u16* __restrict__ Bt,
    int M, int Nc, int K,
    void* __restrict__ Op, const float* __restrict__ aux, const float* __restrict__ dtp)
{
  __shared__ u16 As[128*32];
  __shared__ u16 Bs[128*32];
  const int tid = threadIdx.x, wid = tid>>6, lane = tid&63;
  const int g = lane>>4, l = lane&15;
  const int row0 = blockIdx.x*128, col0 = blockIdx.y*128;
  const int wr = (wid&1)*64, wc = (wid>>1)*64;
  const int l3 = l & 3;
  f32x4 acc[4][4] = {};
  for (int k0 = 0; k0 < K; k0 += 32){
    __syncthreads();
    #pragma unroll
    for (int i=0;i<2;i++){
      int ch0 = i*256 + wid*64;
      int ch = ch0 + lane;
      int r = ch >> 2, c = ch & 3;
      int cs = c ^ (r & 3);
      gld16(A  + (size_t)(row0+r)*K + k0 + cs*8, (char*)As + ch0*16);
      gld16(Bt + (size_t)(col0+r)*K + k0 + cs*8, (char*)Bs + ch0*16);
    }
    __syncthreads();
    bf16x8 a[4], b[4];
    #pragma unroll
    for (int i=0;i<4;i++) a[i] = *(const bf16x8*)(As + (wr + i*16 + l)*32 + (g^l3)*8);
    #pragma unroll
    for (int j=0;j<4;j++) b[j] = *(const bf16x8*)(Bs + (wc + j*16 + l)*32 + (g^l3)*8);
    #pragma unroll
    for (int i=0;i<4;i++)
      #pragma unroll
      for (int j=0;j<4;j++)
        acc[i][j] = __builtin_amdgcn_mfma_f32_16x16x32_bf16(a[i], b[j], acc[i][j], 0, 0, 0);
  }
  #pragma unroll
  for (int i=0;i<4;i++)
   #pragma unroll
   for (int j=0;j<4;j++)
    #pragma unroll
    for (int r=0;r<4;r++){
      int row = row0 + wr + i*16 + g*4 + r;
      int col = col0 + wc + j*16 + l;
      float v = acc[i][j][r];
      int qk = col >> 10, c = col & 1023;
      int bb = row >> 11, n = row & 2047, h = c >> 6, d = c & 63;
      u16* P = (u16*)Op;
      if (qk == 2){
        P[(size_t)8388608 + (((size_t)(bb*16 + h))*64 + d)*2048 + n] = f2bf(v);
      } else {
        float phi = v > 0.f ? v + 1.f : __expf(v);
        P[(size_t)qk*4194304 + (((size_t)(bb*16 + h))*2048 + n)*64 + d] = f2bf(phi);
      }
    }
}

// ---------- wide-tile GEMM for Wup: 256x128 tile, 128x64 per wave, fused silu(G)*U ----------
// A = Qn2 [4096][1024], Bt = WupT [8192][1024] (G/U interleaved), Op = Hf [4096][4096] bf16.
// Intensity 42.7 FLOP/B from LDS (vs 32 for 64x64 waves); 32 MFMA per wave per barrier.
__global__ __launch_bounds__(256, 2) void gemm_wide_up(
    const u16* __restrict__ A, const u16* __restrict__ Bt, u16* __restrict__ Op)
{
  __shared__ u16 As[256*32];   // 16KB
  __shared__ u16 Bs[128*32];   // 8KB
  const int tid = threadIdx.x, wid = tid>>6, lane = tid&63;
  const int g = lane>>4, l = lane&15, l3 = l&3;
  // group-of-8 swizzle over grid (16 M-blocks x 64 N-blocks), 1D launch of 1024
  const int bid = blockIdx.x;
  const int bx = bid & 15;
  const int by = (bid>>7)*8 + ((bid>>4) & 7);
  const int row0 = bx*256, col0 = by*128;
  const int wr = (wid&1)*128, wc = (wid>>1)*64;
  f32x4 acc[8][4] = {};
  for (int k0 = 0; k0 < 1024; k0 += 32){
    __syncthreads();
    #pragma unroll
    for (int i=0;i<4;i++){
      int ch0 = i*256 + wid*64;
      int ch = ch0 + lane;
      int r = ch >> 2, c = ch & 3;
      int cs = c ^ (r & 3);
      gld16(A + (size_t)(row0+r)*1024 + k0 + cs*8, (char*)As + ch0*16);
    }
    #pragma unroll
    for (int i=0;i<2;i++){
      int ch0 = i*256 + wid*64;
      int ch = ch0 + lane;
      int r = ch >> 2, c = ch & 3;
      int cs = c ^ (r & 3);
      gld16(Bt + (size_t)(col0+r)*1024 + k0 + cs*8, (char*)Bs + ch0*16);
    }
    __syncthreads();
    bf16x8 a[8], b[4];
    #pragma unroll
    for (int i=0;i<8;i++) a[i] = *(const bf16x8*)(As + (wr + i*16 + l)*32 + (g^l3)*8);
    #pragma unroll
    for (int j=0;j<4;j++) b[j] = *(const bf16x8*)(Bs + (wc + j*16 + l)*32 + (g^l3)*8);
    #pragma unroll
    for (int i=0;i<8;i++)
      #pragma unroll
      for (int j=0;j<4;j++)
        acc[i][j] = __builtin_amdgcn_mfma_f32_16x16x32_bf16(a[i], b[j], acc[i][j], 0, 0, 0);
  }
  #pragma unroll
  for (int i=0;i<8;i++)
   #pragma unroll
   for (int jj=0;jj<4;jj+=2)
    #pragma unroll
    for (int r=0;r<4;r++){
      int row = row0 + wr + i*16 + g*4 + r;
      int pair = (col0 + wc + jj*16) >> 5;
      float G = acc[i][jj][r], U = acc[i][jj+1][r];
      float hf = G/(1.f+__expf(-G))*U;
      Op[(size_t)row*4096 + pair*16 + l] = f2bf(hf);
    }
}

// ---------- split-K GEMM: fp32 partial per z-slice (no atomics) ----------
__global__ __launch_bounds__(256, 3) void gemm_part(
    const u16* __restrict__ A, const u16* __restrict__ Bt,
    int Nc, int K, int Ks, float* __restrict__ Op)
{
  __shared__ u16 As[128*32];
  __shared__ u16 Bs[128*32];
  const int tid = threadIdx.x, wid = tid>>6, lane = tid&63;
  const int g = lane>>4, l = lane&15;
  const int row0 = blockIdx.x*128, col0 = blockIdx.y*128;
  const int kbase = blockIdx.z*Ks;
  const int wr = (wid&1)*64, wc = (wid>>1)*64;
  const int l3 = l & 3;
  f32x4 acc[4][4] = {};
  for (int k0 = kbase; k0 < kbase + Ks; k0 += 32){
    __syncthreads();
    #pragma unroll
    for (int i=0;i<2;i++){
      int ch0 = i*256 + wid*64;
      int ch = ch0 + lane;
      int r = ch >> 2, c = ch & 3;
      int cs = c ^ (r & 3);
      gld16(A  + (size_t)(row0+r)*K + k0 + cs*8, (char*)As + ch0*16);
      gld16(Bt + (size_t)(col0+r)*K + k0 + cs*8, (char*)Bs + ch0*16);
    }
    __syncthreads();
    bf16x8 a[4], b[4];
    #pragma unroll
    for (int i=0;i<4;i++) a[i] = *(const bf16x8*)(As + (wr + i*16 + l)*32 + (g^l3)*8);
    #pragma unroll
    for (int j=0;j<4;j++) b[j] = *(const bf16x8*)(Bs + (wc + j*16 + l)*32 + (g^l3)*8);
    #pragma unroll
    for (int i=0;i<4;i++)
      #pragma unroll
      for (int j=0;j<4;j++)
        acc[i][j] = __builtin_amdgcn_mfma_f32_16x16x32_bf16(a[i], b[j], acc[i][j], 0, 0, 0);
  }
  float* P = Op + (size_t)blockIdx.z*4194304;
  #pragma unroll
  for (int i=0;i<4;i++)
   #pragma unroll
   for (int j=0;j<4;j++)
    #pragma unroll
    for (int r=0;r<4;r++){
      int row = row0 + wr + i*16 + g*4 + r;
      int col = col0 + wc + j*16 + l;
      P[(size_t)row*Nc + col] = acc[i][j][r];
    }
}

// ---------- out = Qint + Pd0 + Pd1 ----------
__global__ __launch_bounds__(256) void reduce_out(const float* __restrict__ Qint,
    const float* __restrict__ P, float* __restrict__ out){
  size_t i = (size_t)blockIdx.x*256 + threadIdx.x;
  float4 a  = ((const float4*)Qint)[i];
  float4 p0 = ((const float4*)P)[i];
  float4 p1 = ((const float4*)(P + 4194304))[i];
  float4 o;
  o.x = a.x + p0.x + p1.x; o.y = a.y + p0.y + p1.y;
  o.z = a.z + p0.z + p1.z; o.w = a.w + p0.w + p1.w;
  ((float4*)out)[i] = o;
}

// ---------- linear attention with relu^2, flash-style ----------
// LDS = 16+16+16+32 = 80KB -> 2 blocks/CU.
__global__ __launch_bounds__(256, 2) void attn_kernel(
    const u16* __restrict__ PhiQ, const u16* __restrict__ PhiK,
    const u16* __restrict__ Vt, u16* __restrict__ Mb)
{
  __shared__ u16 sQ[2][128][32];
  __shared__ u16 sK[2][128][32];
  __shared__ u16 sV[4][64][32];
  __shared__ u16 sW[128*128];
  const int tid = threadIdx.x, wid = tid>>6, lane = tid&63;
  const int g = lane>>4, l = lane&15;
  const int l3 = l & 3;
  const int q0 = blockIdx.x*128, bh = blockIdx.y;
  const u16* Q  = PhiQ + (size_t)bh*2048*64;
  const u16* Kb = PhiK + (size_t)bh*2048*64;
  const u16* V  = Vt   + (size_t)bh*64*2048;
  #pragma unroll
  for (int ks=0; ks<2; ks++)
    #pragma unroll
    for (int i=0;i<2;i++){
      int ch0 = i*256 + wid*64;
      int ch = ch0 + lane;
      int r = ch >> 2, q = ch & 3;
      int qs = q ^ (r & 3);
      gld16(Q + (size_t)(q0+r)*64 + ks*32 + qs*8, (char*)&sQ[ks][0][0] + ch0*16);
    }
  f32x4 accO[2][4] = {};
  float rsum[8] = {0.f,0.f,0.f,0.f,0.f,0.f,0.f,0.f};
  for (int m0 = 0; m0 < 2048; m0 += 128){
    __syncthreads();   // prior-iter reads of sK/sV/sW done
    #pragma unroll
    for (int ks=0; ks<2; ks++)
      #pragma unroll
      for (int i=0;i<2;i++){
        int ch0 = i*256 + wid*64;
        int ch = ch0 + lane;
        int r = ch >> 2, q = ch & 3;
        int qs = q ^ (r & 3);
        gld16(Kb + (size_t)(m0+r)*64 + ks*32 + qs*8, (char*)&sK[ks][0][0] + ch0*16);
      }
    #pragma unroll
    for (int c=0; c<4; c++){
      int ch0 = wid*64;
      int ch = ch0 + lane;
      int d = ch >> 2, q = ch & 3;
      int qs = q ^ (d & 3);
      gld16(V + (size_t)d*2048 + m0 + c*32 + qs*8, (char*)&sV[c][0][0] + ch0*16);
    }
    __syncthreads();   // staging visible (barrier drains vmcnt)
    // S^T = K_tile @ Q_tile^T ; wave strip: m rows [wid*32, wid*32+32)
    f32x4 st[2][8] = {};
    bf16x8 ak[2][2];
    #pragma unroll
    for (int rt=0;rt<2;rt++)
      #pragma unroll
      for (int ks=0;ks<2;ks++)
        ak[rt][ks] = *(const bf16x8*)&sK[ks][wid*32 + rt*16 + l][(g^l3)*8];
    #pragma unroll
    for (int ct=0;ct<8;ct++){
      #pragma unroll
      for (int ks=0;ks<2;ks++){
        bf16x8 bq = *(const bf16x8*)&sQ[ks][ct*16 + l][(g^l3)*8];
        st[0][ct] = __builtin_amdgcn_mfma_f32_16x16x32_bf16(ak[0][ks], bq, st[0][ct], 0,0,0);
        st[1][ct] = __builtin_amdgcn_mfma_f32_16x16x32_bf16(ak[1][ks], bq, st[1][ct], 0,0,0);
      }
    }
    // W = relu(S)^2 -> bf16 into swizzled sW; col-sum (over m) into rsum
    #pragma unroll
    for (int ct=0;ct<8;ct++){
      float part = 0.f;
      #pragma unroll
      for (int rt=0;rt<2;rt++){
        float s0 = fmaxf(st[rt][ct][0], 0.f), s1 = fmaxf(st[rt][ct][1], 0.f);
        float s2 = fmaxf(st[rt][ct][2], 0.f), s3 = fmaxf(st[rt][ct][3], 0.f);
        float w0 = s0*s0, w1 = s1*s1, w2 = s2*s2, w3 = s3*s3;
        part += w0 + w1 + w2 + w3;
        int n = ct*16 + l;
        int mblk = wid*4 + rt*2 + (g>>1);      // m>>3
        ushort4 w4;
        w4.x = f2bf(w0); w4.y = f2bf(w1); w4.z = f2bf(w2); w4.w = f2bf(w3);
        *(ushort4*)(sW + n*128 + ((mblk ^ l)*8) + (g&1)*4) = w4;
      }
      rsum[ct] += part;
    }
    __syncthreads();   // sW fully written
    // Attr += W @ V : rows n in [wid*32,+32), cols d 0..63, K=128 over m
    #pragma unroll
    for (int ks=0;ks<4;ks++){
      int n0 = wid*32 + l, n1 = wid*32 + 16 + l;
      bf16x8 aw0 = *(const bf16x8*)(sW + n0*128 + (((ks*4+g) ^ (n0&15))*8));
      bf16x8 aw1 = *(const bf16x8*)(sW + n1*128 + (((ks*4+g) ^ (n1&15))*8));
      #pragma unroll
      for (int ct=0;ct<4;ct++){
        bf16x8 bv = *(const bf16x8*)&sV[ks][ct*16 + l][(g^l3)*8];
        accO[0][ct] = __builtin_amdgcn_mfma_f32_16x16x32_bf16(aw0, bv, accO[0][ct], 0,0,0);
        accO[1][ct] = __builtin_amdgcn_mfma_f32_16x16x32_bf16(aw1, bv, accO[1][ct], 0,0,0);
      }
    }
  }
  // finalize Norm: reduce rsum over g-groups then across waves (reuse sW as scratch)
  __syncthreads();
  float* sRS = (float*)sW;            // [4][128]
  float* sNorm = ((float*)sW) + 512;  // [128]
  #pragma unroll
  for (int ct=0;ct<8;ct++){
    float v = rsum[ct];
    v += __shfl_xor(v, 16);
    v += __shfl_xor(v, 32);
    rsum[ct] = v;
  }
  if (g == 0){
    #pragma unroll
    for (int ct=0;ct<8;ct++) sRS[wid*128 + ct*16 + l] = rsum[ct];
  }
  __syncthreads();
  if (tid < 128) sNorm[tid] = sRS[tid] + sRS[128+tid] + sRS[256+tid] + sRS[384+tid] + 1.0f;
  __syncthreads();
  const int bb = bh >> 4, h = bh & 15;
  #pragma unroll
  for (int rt=0;rt<2;rt++)
   #pragma unroll
   for (int ct=0;ct<4;ct++)
    #pragma unroll
    for (int r=0;r<4;r++){
      int n = wid*32 + rt*16 + g*4 + r;
      int d = ct*16 + l;
      float norm = sNorm[n];
      float vv = bf2f(V[(size_t)d*2048 + q0 + n]);
      float mv = accO[rt][ct][r]/norm - vv;
      Mb[((size_t)(bb*2048) + q0 + n)*1024 + h*64 + d] = f2bf(mv);
    }
}

// ---------- depthwise conv along n (KS=3, pad=1, per batch) ----------
__global__ __launch_bounds__(256) void conv_kernel(const u16* __restrict__ Hf, const float* __restrict__ w,
                                                   u16* __restrict__ Cv){
  int row = blockIdx.y;
  int n = row & 2047;
  int c0 = (blockIdx.x*256 + threadIdx.x)*8;
  us8v h0 = {0,0,0,0,0,0,0,0}, h2 = {0,0,0,0,0,0,0,0};
  us8v h1 = *(const us8v*)(Hf + (size_t)row*4096 + c0);
  if (n > 0)    h0 = *(const us8v*)(Hf + (size_t)(row-1)*4096 + c0);
  if (n < 2047) h2 = *(const us8v*)(Hf + (size_t)(row+1)*4096 + c0);
  us8v o;
  #pragma unroll
  for (int e=0;e<8;e++){
    int c = c0 + e;
    float acc = bf2f(h0[e])*w[c*3+0] + bf2f(h1[e])*w[c*3+1] + bf2f(h2[e])*w[c*3+2];
    o[e] = f2bf(acc);
  }
  *(us8v*)(Cv + (size_t)row*4096 + c0) = o;
}

extern "C" void kernel_launch(void* const* d_in, const int* in_sizes, int n_in,
                              void* d_out, int out_size, void* d_ws, size_t ws_size,
                              hipStream_t stream)
{
  const float* Q_in  = (const float*)d_in[0];
  const float* X     = (const float*)d_in[1];
  const float* Wq    = (const float*)d_in[2];
  const float* Wk    = (const float*)d_in[3];
  const float* Wv    = (const float*)d_in[4];
  const float* Wo    = (const float*)d_in[5];
  const float* Wup   = (const float*)d_in[6];
  const float* convw = (const float*)d_in[7];
  const float* Wdown = (const float*)d_in[8];
  const float* g1    = (const float*)d_in[9];
  const float* b1    = (const float*)d_in[10];
  const float* g2    = (const float*)d_in[11];
  const float* b2    = (const float*)d_in[12];
  const float* dt    = (const float*)d_in[13];
  float* out = (float*)d_out;

  char* ws = (char*)d_ws;
  const size_t MB = (size_t)1 << 20;
  u16* HcB   = (u16*)(ws + 0*MB);     // 8MB  (dead after QKV gemm)
  u16* WqkvT = (u16*)(ws + 8*MB);     // 6MB  [3072][1024] (dead after QKV gemm)
  u16* WoT   = (u16*)(ws + 14*MB);    // 2MB  (dead after Wo gemm)
  u16* PhiQ  = (u16*)(ws + 16*MB);    // 8MB  } contiguous: PhiQ,PhiK,Vt (dead after attn)
  u16* Vt    = (u16*)(ws + 32*MB);    // 8MB
  u16* Mb    = (u16*)(ws + 40*MB);    // 8MB  (dead after Wo gemm)
  float* Po  = (float*)(ws + 48*MB);  // 32MB 2x fp32 partials (dead after ln2)
  u16* WupT  = (u16*)(ws + 80*MB);    // 16MB
  u16* WdT   = (u16*)(ws + 96*MB);    // 8MB
  float* Qint = (float*)(ws + 104*MB);// 16MB
  u16* Qn2   = (u16*)(ws + 120*MB);   // 8MB  (dead after Wup gemm)
  u16* Hf    = (u16*)(ws + 0*MB);     // 32MB (written after Wup gemm; old region dead)
  u16* Cv    = (u16*)(ws + 40*MB);    // 32MB (over Mb+Po, both dead by conv)
  float* Pd  = (float*)(ws + 0*MB);   // 32MB 2x fp32 partials (over Hf, dead after conv)
  u16* PhiK  = PhiQ + 4194304;

  dim3 tb(32, 8);
  tr_cvt<<<dim3(32, 32),  tb, 0, stream>>>(Wq,    WqkvT,               1024, 1024);
  tr_cvt<<<dim3(32, 32),  tb, 0, stream>>>(Wk,    WqkvT + 1024*1024,   1024, 1024);
  tr_cvt<<<dim3(32, 32),  tb, 0, stream>>>(Wv,    WqkvT + 2*1024*1024, 1024, 1024);
  tr_cvt<<<dim3(32, 32),  tb, 0, stream>>>(Wo,    WoT, 1024, 1024);
  tr_cvt_up<<<dim3(256, 32), tb, 0, stream>>>(Wup, WupT);
  tr_cvt<<<dim3(32, 128), tb, 0, stream>>>(Wdown, WdT, 4096, 1024);

  ln_kernel<<<4096, 256, 0, stream>>>(Q_in, X, g1, b1, HcB);

  // fused QKV projection: [4096][1024] @ [3072][1024]^T
  gemm_bt<5><<<dim3(32, 24), 256, 0, stream>>>(HcB, WqkvT, 4096, 3072, 1024, PhiQ, nullptr, nullptr);

  attn_kernel<<<dim3(16, 32), 256, 0, stream>>>(PhiQ, PhiK, Vt, Mb);

  // Wo projection, split-K=2 -> fp32 partials
  gemm_part<<<dim3(32, 8, 2), 256, 0, stream>>>(Mb, WoT, 1024, 1024, 512, Po);

  // Qint = Q_in + softplus(dt)*(Po0+Po1); Qn2 = LN(Qint)
  ln2_kernel<<<4096, 256, 0, stream>>>(Po, Q_in, dt, g2, b2, Qint, Qn2);

  // Wup with fused silu(G)*U epilogue -> Hf [4096][4096], wide 256x128 tiles
  gemm_wide_up<<<1024, 256, 0, stream>>>(Qn2, WupT, Hf);

  conv_kernel<<<dim3(2, 4096), 256, 0, stream>>>(Hf, convw, Cv);

  // Wdown split-K=2 -> fp32 partials, then out = Qint + Pd0 + Pd1
  gemm_part<<<dim3(32, 8, 2), 256, 0, stream>>>(Cv, WdT, 1024, 4096, 2048, Pd);
  reduce_out<<<4096, 256, 0, stream>>>(Qint, Pd, out);
}

// Round 5
// 434.442 us; speedup vs baseline: 1.0395x; 1.0395x over previous
//
#include <hip/hip_runtime.h>

typedef unsigned short u16;
typedef __attribute__((ext_vector_type(8))) __bf16 bf16x8;
typedef __attribute__((ext_vector_type(4))) float f32x4;
typedef __attribute__((ext_vector_type(8))) unsigned short us8v;

__device__ __forceinline__ u16 f2bf(float x){
  union { float f; unsigned u; } v; v.f = x;
  unsigned r = v.u + 0x7fffu + ((v.u >> 16) & 1u);
  return (u16)(r >> 16);
}
__device__ __forceinline__ float bf2f(u16 h){
  union { unsigned u; float f; } v; v.u = ((unsigned)h) << 16;
  return v.f;
}
// async global->LDS, 16B per lane. lds ptr must be wave-uniform; HW writes base + lane*16.
__device__ __forceinline__ void gld16(const void* g, void* l){
  __builtin_amdgcn_global_load_lds((const __attribute__((address_space(1))) unsigned int*)g,
                                   (__attribute__((address_space(3))) unsigned int*)l, 16, 0, 0);
}

// ---------- all weight transposes in ONE kernel (fewer dispatch gaps) ----------
// blocks 0..4095: Wq/Wk/Wv/Wo (1024 each, 1024x1024)
// blocks 4096..12287: Wup with G/U interleave (1024x8192)
// blocks 12288..16383: Wdown (4096x1024)
__global__ __launch_bounds__(256) void tr_all(
    const float* __restrict__ Wq, const float* __restrict__ Wk,
    const float* __restrict__ Wv, const float* __restrict__ Wo,
    const float* __restrict__ Wup, const float* __restrict__ Wdown,
    u16* __restrict__ WqkvT, u16* __restrict__ WoT,
    u16* __restrict__ WupT, u16* __restrict__ WdT)
{
  __shared__ float t[32][33];
  int tx = threadIdx.x, ty = threadIdx.y;
  int id = blockIdx.x;
  if (id < 4096){
    int w = id >> 10, b = id & 1023;
    int c0 = (b & 31)*32, r0 = (b >> 5)*32;
    const float* S = (w==0)?Wq:(w==1)?Wk:(w==2)?Wv:Wo;
    u16* D = (w==3)? WoT : (WqkvT + (size_t)w*1024*1024);
    #pragma unroll
    for (int j=0;j<32;j+=8) t[ty+j][tx] = S[(size_t)(r0+ty+j)*1024 + (c0+tx)];
    __syncthreads();
    #pragma unroll
    for (int j=0;j<32;j+=8) D[(size_t)(c0+ty+j)*1024 + (r0+tx)] = f2bf(t[tx][ty+j]);
  } else if (id < 12288){
    int b = id - 4096;
    int c0 = (b & 255)*32, r0 = (b >> 8)*32;
    #pragma unroll
    for (int j=0;j<32;j+=8) t[ty+j][tx] = Wup[(size_t)(r0+ty+j)*8192 + (c0+tx)];
    __syncthreads();
    #pragma unroll
    for (int j=0;j<32;j+=8){
      int c = c0 + ty + j;
      int rdst = (c < 4096) ? ((c>>4)*32 + (c&15)) : (((c-4096)>>4)*32 + 16 + (c&15));
      WupT[(size_t)rdst*1024 + (r0+tx)] = f2bf(t[tx][ty+j]);
    }
  } else {
    int b = id - 12288;
    int c0 = (b & 31)*32, r0 = (b >> 5)*32;
    #pragma unroll
    for (int j=0;j<32;j+=8) t[ty+j][tx] = Wdown[(size_t)(r0+ty+j)*1024 + (c0+tx)];
    __syncthreads();
    #pragma unroll
    for (int j=0;j<32;j+=8) WdT[(size_t)(c0+ty+j)*4096 + (r0+tx)] = f2bf(t[tx][ty+j]);
  }
}

// ---------- layernorm (+optional residual X), fp32 in -> bf16 out. D=1024, 256 thr ----------
__global__ __launch_bounds__(256) void ln_kernel(const float* __restrict__ Q, const float* __restrict__ X,
    const float* __restrict__ g, const float* __restrict__ b, u16* __restrict__ O){
  int row = blockIdx.x, tid = threadIdx.x;
  const float4 x = ((const float4*)(Q + (size_t)row*1024))[tid];
  float s = x.x + x.y + x.z + x.w;
  float sq = x.x*x.x + x.y*x.y + x.z*x.z + x.w*x.w;
  #pragma unroll
  for (int o=32;o>0;o>>=1){ s += __shfl_xor(s, o); sq += __shfl_xor(sq, o); }
  __shared__ float ss[4], ssq[4];
  int wid = tid>>6;
  if ((tid&63)==0){ ss[wid]=s; ssq[wid]=sq; }
  __syncthreads();
  s = ss[0]+ss[1]+ss[2]+ss[3]; sq = ssq[0]+ssq[1]+ssq[2]+ssq[3];
  float mu = s*(1.0f/1024.0f);
  float var = sq*(1.0f/1024.0f) - mu*mu;
  float rstd = rsqrtf(var + 1e-5f);
  float4 xx = make_float4(0.f,0.f,0.f,0.f);
  if (X) xx = ((const float4*)(X + (size_t)row*1024))[tid];
  float4 gv = ((const float4*)g)[tid];
  float4 bv = ((const float4*)b)[tid];
  ushort4 o;
  o.x = f2bf((x.x-mu)*rstd*gv.x + bv.x + xx.x);
  o.y = f2bf((x.y-mu)*rstd*gv.y + bv.y + xx.y);
  o.z = f2bf((x.z-mu)*rstd*gv.z + bv.z + xx.z);
  o.w = f2bf((x.w-mu)*rstd*gv.w + bv.w + xx.w);
  ((ushort4*)(O + (size_t)row*1024))[tid] = o;
}

// ---------- ln2: Qint = Q_in + softplus(dt)*(P0+P1); Qn2 = LN(Qint)*g+b ----------
__global__ __launch_bounds__(256) void ln2_kernel(const float* __restrict__ P,
    const float* __restrict__ Qin, const float* __restrict__ dtp,
    const float* __restrict__ g, const float* __restrict__ b,
    float* __restrict__ Qint, u16* __restrict__ Qn2){
  int row = blockIdx.x, tid = threadIdx.x;
  float sp = log1pf(__expf(dtp[0]));
  size_t off = (size_t)row*1024;
  float4 p0 = ((const float4*)(P + off))[tid];
  float4 p1 = ((const float4*)(P + 4194304 + off))[tid];
  float4 q  = ((const float4*)(Qin + off))[tid];
  float4 x;
  x.x = q.x + sp*(p0.x+p1.x); x.y = q.y + sp*(p0.y+p1.y);
  x.z = q.z + sp*(p0.z+p1.z); x.w = q.w + sp*(p0.w+p1.w);
  ((float4*)(Qint + off))[tid] = x;
  float s = x.x + x.y + x.z + x.w;
  float sq = x.x*x.x + x.y*x.y + x.z*x.z + x.w*x.w;
  #pragma unroll
  for (int o=32;o>0;o>>=1){ s += __shfl_xor(s, o); sq += __shfl_xor(sq, o); }
  __shared__ float ss[4], ssq[4];
  int wid = tid>>6;
  if ((tid&63)==0){ ss[wid]=s; ssq[wid]=sq; }
  __syncthreads();
  s = ss[0]+ss[1]+ss[2]+ss[3]; sq = ssq[0]+ssq[1]+ssq[2]+ssq[3];
  float mu = s*(1.0f/1024.0f);
  float var = sq*(1.0f/1024.0f) - mu*mu;
  float rstd = rsqrtf(var + 1e-5f);
  float4 gv = ((const float4*)g)[tid];
  float4 bv = ((const float4*)b)[tid];
  ushort4 o;
  o.x = f2bf((x.x-mu)*rstd*gv.x + bv.x);
  o.y = f2bf((x.y-mu)*rstd*gv.y + bv.y);
  o.z = f2bf((x.z-mu)*rstd*gv.z + bv.z);
  o.w = f2bf((x.w-mu)*rstd*gv.w + bv.w);
  ((ushort4*)(Qn2 + off))[tid] = o;
}

// ---------- fused QKV GEMM, A[4096][1024] @ WqkvT[3072][1024]^T ----------
// col<1024 -> phi->PhiQ, <2048 -> phi->PhiK, else Vt (Op = PhiQ base, regions contiguous)
__global__ __launch_bounds__(256, 3) void gemm_qkv(
    const u16* __restrict__ A, const u16* __restrict__ Bt, void* __restrict__ Op)
{
  __shared__ u16 As[128*32];
  __shared__ u16 Bs[128*32];
  const int tid = threadIdx.x, wid = tid>>6, lane = tid&63;
  const int g = lane>>4, l = lane&15;
  const int row0 = blockIdx.x*128, col0 = blockIdx.y*128;
  const int wr = (wid&1)*64, wc = (wid>>1)*64;
  const int l3 = l & 3;
  f32x4 acc[4][4] = {};
  for (int k0 = 0; k0 < 1024; k0 += 32){
    __syncthreads();
    #pragma unroll
    for (int i=0;i<2;i++){
      int ch0 = i*256 + wid*64;
      int ch = ch0 + lane;
      int r = ch >> 2, c = ch & 3;
      int cs = c ^ (r & 3);
      gld16(A  + (size_t)(row0+r)*1024 + k0 + cs*8, (char*)As + ch0*16);
      gld16(Bt + (size_t)(col0+r)*1024 + k0 + cs*8, (char*)Bs + ch0*16);
    }
    __syncthreads();
    bf16x8 a[4], b[4];
    #pragma unroll
    for (int i=0;i<4;i++) a[i] = *(const bf16x8*)(As + (wr + i*16 + l)*32 + (g^l3)*8);
    #pragma unroll
    for (int j=0;j<4;j++) b[j] = *(const bf16x8*)(Bs + (wc + j*16 + l)*32 + (g^l3)*8);
    #pragma unroll
    for (int i=0;i<4;i++)
      #pragma unroll
      for (int j=0;j<4;j++)
        acc[i][j] = __builtin_amdgcn_mfma_f32_16x16x32_bf16(a[i], b[j], acc[i][j], 0, 0, 0);
  }
  u16* P = (u16*)Op;
  #pragma unroll
  for (int i=0;i<4;i++)
   #pragma unroll
   for (int j=0;j<4;j++){
     int col = col0 + wc + j*16 + l;
     int qk = col >> 10, c = col & 1023;
     int h = c >> 6, d = c & 63;
     int rowb = row0 + wr + i*16 + g*4;
     int bb = rowb >> 11, n = rowb & 2047;
     if (qk == 2){
       ushort4 vs;
       vs.x = f2bf(acc[i][j][0]); vs.y = f2bf(acc[i][j][1]);
       vs.z = f2bf(acc[i][j][2]); vs.w = f2bf(acc[i][j][3]);
       *(ushort4*)(P + (size_t)8388608 + (((size_t)(bb*16 + h))*64 + d)*2048 + n) = vs;
     } else {
       #pragma unroll
       for (int r=0;r<4;r++){
         float v = acc[i][j][r];
         float phi = v > 0.f ? v + 1.f : __expf(v);
         P[(size_t)qk*4194304 + (((size_t)(bb*16 + h))*2048 + (n+r))*64 + d] = f2bf(phi);
       }
     }
   }
}

// ---------- wide-tile GEMM for Wup: 256x128 tile, 128x64 per wave, fused silu(G)*U ----------
__global__ __launch_bounds__(256, 2) void gemm_wide_up(
    const u16* __restrict__ A, const u16* __restrict__ Bt, u16* __restrict__ Op)
{
  __shared__ u16 As[256*32];   // 16KB
  __shared__ u16 Bs[128*32];   // 8KB
  const int tid = threadIdx.x, wid = tid>>6, lane = tid&63;
  const int g = lane>>4, l = lane&15, l3 = l&3;
  const int bid = blockIdx.x;
  const int bx = bid & 15;
  const int by = (bid>>7)*8 + ((bid>>4) & 7);
  const int row0 = bx*256, col0 = by*128;
  const int wr = (wid&1)*128, wc = (wid>>1)*64;
  f32x4 acc[8][4] = {};
  for (int k0 = 0; k0 < 1024; k0 += 32){
    __syncthreads();
    #pragma unroll
    for (int i=0;i<4;i++){
      int ch0 = i*256 + wid*64;
      int ch = ch0 + lane;
      int r = ch >> 2, c = ch & 3;
      int cs = c ^ (r & 3);
      gld16(A + (size_t)(row0+r)*1024 + k0 + cs*8, (char*)As + ch0*16);
    }
    #pragma unroll
    for (int i=0;i<2;i++){
      int ch0 = i*256 + wid*64;
      int ch = ch0 + lane;
      int r = ch >> 2, c = ch & 3;
      int cs = c ^ (r & 3);
      gld16(Bt + (size_t)(col0+r)*1024 + k0 + cs*8, (char*)Bs + ch0*16);
    }
    __syncthreads();
    bf16x8 a[8], b[4];
    #pragma unroll
    for (int i=0;i<8;i++) a[i] = *(const bf16x8*)(As + (wr + i*16 + l)*32 + (g^l3)*8);
    #pragma unroll
    for (int j=0;j<4;j++) b[j] = *(const bf16x8*)(Bs + (wc + j*16 + l)*32 + (g^l3)*8);
    #pragma unroll
    for (int i=0;i<8;i++)
      #pragma unroll
      for (int j=0;j<4;j++)
        acc[i][j] = __builtin_amdgcn_mfma_f32_16x16x32_bf16(a[i], b[j], acc[i][j], 0, 0, 0);
  }
  #pragma unroll
  for (int i=0;i<8;i++)
   #pragma unroll
   for (int jj=0;jj<4;jj+=2)
    #pragma unroll
    for (int r=0;r<4;r++){
      int row = row0 + wr + i*16 + g*4 + r;
      int pair = (col0 + wc + jj*16) >> 5;
      float G = acc[i][jj][r], U = acc[i][jj+1][r];
      float hf = G/(1.f+__expf(-G))*U;
      Op[(size_t)row*4096 + pair*16 + l] = f2bf(hf);
    }
}

// ---------- split-K GEMM: fp32 partial per z-slice (no atomics) ----------
__global__ __launch_bounds__(256, 3) void gemm_part(
    const u16* __restrict__ A, const u16* __restrict__ Bt,
    int Nc, int K, int Ks, float* __restrict__ Op)
{
  __shared__ u16 As[128*32];
  __shared__ u16 Bs[128*32];
  const int tid = threadIdx.x, wid = tid>>6, lane = tid&63;
  const int g = lane>>4, l = lane&15;
  const int row0 = blockIdx.x*128, col0 = blockIdx.y*128;
  const int kbase = blockIdx.z*Ks;
  const int wr = (wid&1)*64, wc = (wid>>1)*64;
  const int l3 = l & 3;
  f32x4 acc[4][4] = {};
  for (int k0 = kbase; k0 < kbase + Ks; k0 += 32){
    __syncthreads();
    #pragma unroll
    for (int i=0;i<2;i++){
      int ch0 = i*256 + wid*64;
      int ch = ch0 + lane;
      int r = ch >> 2, c = ch & 3;
      int cs = c ^ (r & 3);
      gld16(A  + (size_t)(row0+r)*K + k0 + cs*8, (char*)As + ch0*16);
      gld16(Bt + (size_t)(col0+r)*K + k0 + cs*8, (char*)Bs + ch0*16);
    }
    __syncthreads();
    bf16x8 a[4], b[4];
    #pragma unroll
    for (int i=0;i<4;i++) a[i] = *(const bf16x8*)(As + (wr + i*16 + l)*32 + (g^l3)*8);
    #pragma unroll
    for (int j=0;j<4;j++) b[j] = *(const bf16x8*)(Bs + (wc + j*16 + l)*32 + (g^l3)*8);
    #pragma unroll
    for (int i=0;i<4;i++)
      #pragma unroll
      for (int j=0;j<4;j++)
        acc[i][j] = __builtin_amdgcn_mfma_f32_16x16x32_bf16(a[i], b[j], acc[i][j], 0, 0, 0);
  }
  float* P = Op + (size_t)blockIdx.z*4194304;
  #pragma unroll
  for (int i=0;i<4;i++)
   #pragma unroll
   for (int j=0;j<4;j++)
    #pragma unroll
    for (int r=0;r<4;r++){
      int row = row0 + wr + i*16 + g*4 + r;
      int col = col0 + wc + j*16 + l;
      P[(size_t)row*Nc + col] = acc[i][j][r];
    }
}

// ---------- out = Qint + Pd0 + Pd1 ----------
__global__ __launch_bounds__(256) void reduce_out(const float* __restrict__ Qint,
    const float* __restrict__ P, float* __restrict__ out){
  size_t i = (size_t)blockIdx.x*256 + threadIdx.x;
  float4 a  = ((const float4*)Qint)[i];
  float4 p0 = ((const float4*)P)[i];
  float4 p1 = ((const float4*)(P + 4194304))[i];
  float4 o;
  o.x = a.x + p0.x + p1.x; o.y = a.y + p0.y + p1.y;
  o.z = a.z + p0.z + p1.z; o.w = a.w + p0.w + p1.w;
  ((float4*)out)[i] = o;
}

// ---------- linear attention with relu^2, flash-style ----------
// Q-fragments held in REGISTERS (loop-invariant; 64 VGPRs) -> no sQ, LDS reads 44->28 per wave/iter.
// LDS = sK 16 + sV 16 + sW 32 = 64KB -> 2 blocks/CU.
__global__ __launch_bounds__(256, 2) void attn_kernel(
    const u16* __restrict__ PhiQ, const u16* __restrict__ PhiK,
    const u16* __restrict__ Vt, u16* __restrict__ Mb)
{
  __shared__ u16 sK[2][128][32];
  __shared__ u16 sV[4][64][32];
  __shared__ u16 sW[128*128];
  const int tid = threadIdx.x, wid = tid>>6, lane = tid&63;
  const int g = lane>>4, l = lane&15;
  const int l3 = l & 3;
  const int q0 = blockIdx.x*128, bh = blockIdx.y;
  const u16* Q  = PhiQ + (size_t)bh*2048*64;
  const u16* Kb = PhiK + (size_t)bh*2048*64;
  const u16* V  = Vt   + (size_t)bh*64*2048;
  // Q-fragments direct from global into registers (B-operand layout): bq[ct][ks]
  bf16x8 bq[8][2];
  #pragma unroll
  for (int ct=0;ct<8;ct++)
    #pragma unroll
    for (int ks=0;ks<2;ks++)
      bq[ct][ks] = *(const bf16x8*)(Q + (size_t)(q0 + ct*16 + l)*64 + ks*32 + g*8);
  f32x4 accO[2][4] = {};
  float rsum[8] = {0.f,0.f,0.f,0.f,0.f,0.f,0.f,0.f};
  for (int m0 = 0; m0 < 2048; m0 += 128){
    __syncthreads();   // prior-iter reads of sK/sV/sW done
    #pragma unroll
    for (int ks=0; ks<2; ks++)
      #pragma unroll
      for (int i=0;i<2;i++){
        int ch0 = i*256 + wid*64;
        int ch = ch0 + lane;
        int r = ch >> 2, q = ch & 3;
        int qs = q ^ (r & 3);
        gld16(Kb + (size_t)(m0+r)*64 + ks*32 + qs*8, (char*)&sK[ks][0][0] + ch0*16);
      }
    #pragma unroll
    for (int c=0; c<4; c++){
      int ch0 = wid*64;
      int ch = ch0 + lane;
      int d = ch >> 2, q = ch & 3;
      int qs = q ^ (d & 3);
      gld16(V + (size_t)d*2048 + m0 + c*32 + qs*8, (char*)&sV[c][0][0] + ch0*16);
    }
    __syncthreads();   // staging visible (barrier drains vmcnt)
    // S^T = K_tile @ Q_tile^T ; wave strip: m rows [wid*32, wid*32+32)
    f32x4 st[2][8] = {};
    bf16x8 ak[2][2];
    #pragma unroll
    for (int rt=0;rt<2;rt++)
      #pragma unroll
      for (int ks=0;ks<2;ks++)
        ak[rt][ks] = *(const bf16x8*)&sK[ks][wid*32 + rt*16 + l][(g^l3)*8];
    #pragma unroll
    for (int ct=0;ct<8;ct++){
      #pragma unroll
      for (int ks=0;ks<2;ks++){
        st[0][ct] = __builtin_amdgcn_mfma_f32_16x16x32_bf16(ak[0][ks], bq[ct][ks], st[0][ct], 0,0,0);
        st[1][ct] = __builtin_amdgcn_mfma_f32_16x16x32_bf16(ak[1][ks], bq[ct][ks], st[1][ct], 0,0,0);
      }
    }
    // W = relu(S)^2 -> bf16 into swizzled sW; col-sum (over m) into rsum
    #pragma unroll
    for (int ct=0;ct<8;ct++){
      float part = 0.f;
      #pragma unroll
      for (int rt=0;rt<2;rt++){
        float s0 = fmaxf(st[rt][ct][0], 0.f), s1 = fmaxf(st[rt][ct][1], 0.f);
        float s2 = fmaxf(st[rt][ct][2], 0.f), s3 = fmaxf(st[rt][ct][3], 0.f);
        float w0 = s0*s0, w1 = s1*s1, w2 = s2*s2, w3 = s3*s3;
        part += w0 + w1 + w2 + w3;
        int n = ct*16 + l;
        int mblk = wid*4 + rt*2 + (g>>1);      // m>>3
        ushort4 w4;
        w4.x = f2bf(w0); w4.y = f2bf(w1); w4.z = f2bf(w2); w4.w = f2bf(w3);
        *(ushort4*)(sW + n*128 + ((mblk ^ l)*8) + (g&1)*4) = w4;
      }
      rsum[ct] += part;
    }
    __syncthreads();   // sW fully written
    // Attr += W @ V : rows n in [wid*32,+32), cols d 0..63, K=128 over m
    #pragma unroll
    for (int ks=0;ks<4;ks++){
      int n0 = wid*32 + l, n1 = wid*32 + 16 + l;
      bf16x8 aw0 = *(const bf16x8*)(sW + n0*128 + (((ks*4+g) ^ (n0&15))*8));
      bf16x8 aw1 = *(const bf16x8*)(sW + n1*128 + (((ks*4+g) ^ (n1&15))*8));
      #pragma unroll
      for (int ct=0;ct<4;ct++){
        bf16x8 bv = *(const bf16x8*)&sV[ks][ct*16 + l][(g^l3)*8];
        accO[0][ct] = __builtin_amdgcn_mfma_f32_16x16x32_bf16(aw0, bv, accO[0][ct], 0,0,0);
        accO[1][ct] = __builtin_amdgcn_mfma_f32_16x16x32_bf16(aw1, bv, accO[1][ct], 0,0,0);
      }
    }
  }
  // finalize Norm: reduce rsum over g-groups then across waves (reuse sW as scratch)
  __syncthreads();
  float* sRS = (float*)sW;            // [4][128]
  float* sNorm = ((float*)sW) + 512;  // [128]
  #pragma unroll
  for (int ct=0;ct<8;ct++){
    float v = rsum[ct];
    v += __shfl_xor(v, 16);
    v += __shfl_xor(v, 32);
    rsum[ct] = v;
  }
  if (g == 0){
    #pragma unroll
    for (int ct=0;ct<8;ct++) sRS[wid*128 + ct*16 + l] = rsum[ct];
  }
  __syncthreads();
  if (tid < 128) sNorm[tid] = sRS[tid] + sRS[128+tid] + sRS[256+tid] + sRS[384+tid] + 1.0f;
  __syncthreads();
  const int bb = bh >> 4, h = bh & 15;
  #pragma unroll
  for (int rt=0;rt<2;rt++)
   #pragma unroll
   for (int ct=0;ct<4;ct++)
    #pragma unroll
    for (int r=0;r<4;r++){
      int n = wid*32 + rt*16 + g*4 + r;
      int d = ct*16 + l;
      float norm = sNorm[n];
      float vv = bf2f(V[(size_t)d*2048 + q0 + n]);
      float mv = accO[rt][ct][r]/norm - vv;
      Mb[((size_t)(bb*2048) + q0 + n)*1024 + h*64 + d] = f2bf(mv);
    }
}

// ---------- depthwise conv along n (KS=3, pad=1, per batch) ----------
__global__ __launch_bounds__(256) void conv_kernel(const u16* __restrict__ Hf, const float* __restrict__ w,
                                                   u16* __restrict__ Cv){
  int row = blockIdx.y;
  int n = row & 2047;
  int c0 = (blockIdx.x*256 + threadIdx.x)*8;
  us8v h0 = {0,0,0,0,0,0,0,0}, h2 = {0,0,0,0,0,0,0,0};
  us8v h1 = *(const us8v*)(Hf + (size_t)row*4096 + c0);
  if (n > 0)    h0 = *(const us8v*)(Hf + (size_t)(row-1)*4096 + c0);
  if (n < 2047) h2 = *(const us8v*)(Hf + (size_t)(row+1)*4096 + c0);
  us8v o;
  #pragma unroll
  for (int e=0;e<8;e++){
    int c = c0 + e;
    float acc = bf2f(h0[e])*w[c*3+0] + bf2f(h1[e])*w[c*3+1] + bf2f(h2[e])*w[c*3+2];
    o[e] = f2bf(acc);
  }
  *(us8v*)(Cv + (size_t)row*4096 + c0) = o;
}

extern "C" void kernel_launch(void* const* d_in, const int* in_sizes, int n_in,
                              void* d_out, int out_size, void* d_ws, size_t ws_size,
                              hipStream_t stream)
{
  const float* Q_in  = (const float*)d_in[0];
  const float* X     = (const float*)d_in[1];
  const float* Wq    = (const float*)d_in[2];
  const float* Wk    = (const float*)d_in[3];
  const float* Wv    = (const float*)d_in[4];
  const float* Wo    = (const float*)d_in[5];
  const float* Wup   = (const float*)d_in[6];
  const float* convw = (const float*)d_in[7];
  const float* Wdown = (const float*)d_in[8];
  const float* g1    = (const float*)d_in[9];
  const float* b1    = (const float*)d_in[10];
  const float* g2    = (const float*)d_in[11];
  const float* b2    = (const float*)d_in[12];
  const float* dt    = (const float*)d_in[13];
  float* out = (float*)d_out;

  char* ws = (char*)d_ws;
  const size_t MB = (size_t)1 << 20;
  u16* HcB   = (u16*)(ws + 0*MB);     // 8MB  (dead after QKV gemm)
  u16* WqkvT = (u16*)(ws + 8*MB);     // 6MB  [3072][1024] (dead after QKV gemm)
  u16* WoT   = (u16*)(ws + 14*MB);    // 2MB  (dead after Wo gemm)
  u16* PhiQ  = (u16*)(ws + 16*MB);    // 8MB  } contiguous: PhiQ,PhiK,Vt (dead after attn)
  u16* Vt    = (u16*)(ws + 32*MB);    // 8MB
  u16* Mb    = (u16*)(ws + 40*MB);    // 8MB  (dead after Wo gemm)
  float* Po  = (float*)(ws + 48*MB);  // 32MB 2x fp32 partials (dead after ln2)
  u16* WupT  = (u16*)(ws + 80*MB);    // 16MB
  u16* WdT   = (u16*)(ws + 96*MB);    // 8MB
  float* Qint = (float*)(ws + 104*MB);// 16MB
  u16* Qn2   = (u16*)(ws + 120*MB);   // 8MB  (dead after Wup gemm)
  u16* Hf    = (u16*)(ws + 0*MB);     // 32MB (written after Wup gemm; old region dead)
  u16* Cv    = (u16*)(ws + 40*MB);    // 32MB (over Mb+Po, both dead by conv)
  float* Pd  = (float*)(ws + 0*MB);   // 32MB 2x fp32 partials (over Hf, dead after conv)
  u16* PhiK  = PhiQ + 4194304;

  tr_all<<<16384, dim3(32, 8), 0, stream>>>(Wq, Wk, Wv, Wo, Wup, Wdown,
                                            WqkvT, WoT, WupT, WdT);

  ln_kernel<<<4096, 256, 0, stream>>>(Q_in, X, g1, b1, HcB);

  // fused QKV projection: [4096][1024] @ [3072][1024]^T
  gemm_qkv<<<dim3(32, 24), 256, 0, stream>>>(HcB, WqkvT, PhiQ);

  attn_kernel<<<dim3(16, 32), 256, 0, stream>>>(PhiQ, PhiK, Vt, Mb);

  // Wo projection, split-K=2 -> fp32 partials
  gemm_part<<<dim3(32, 8, 2), 256, 0, stream>>>(Mb, WoT, 1024, 1024, 512, Po);

  // Qint = Q_in + softplus(dt)*(Po0+Po1); Qn2 = LN(Qint)
  ln2_kernel<<<4096, 256, 0, stream>>>(Po, Q_in, dt, g2, b2, Qint, Qn2);

  // Wup with fused silu(G)*U epilogue -> Hf [4096][4096], wide 256x128 tiles
  gemm_wide_up<<<1024, 256, 0, stream>>>(Qn2, WupT, Hf);

  conv_kernel<<<dim3(2, 4096), 256, 0, stream>>>(Hf, convw, Cv);

  // Wdown split-K=2 -> fp32 partials, then out = Qint + Pd0 + Pd1
  gemm_part<<<dim3(32, 8, 2), 256, 0, stream>>>(Cv, WdT, 1024, 4096, 2048, Pd);
  reduce_out<<<4096, 256, 0, stream>>>(Qint, Pd, out);
}

// Round 6
// 389.202 us; speedup vs baseline: 1.1603x; 1.1162x over previous
//
#include <hip/hip_runtime.h>

typedef unsigned short u16;
typedef __attribute__((ext_vector_type(8))) __bf16 bf16x8;
typedef __attribute__((ext_vector_type(4))) float f32x4;
typedef __attribute__((ext_vector_type(8))) unsigned short us8v;

__device__ __forceinline__ u16 f2bf(float x){
  union { float f; unsigned u; } v; v.f = x;
  unsigned r = v.u + 0x7fffu + ((v.u >> 16) & 1u);
  return (u16)(r >> 16);
}
__device__ __forceinline__ float bf2f(u16 h){
  union { unsigned u; float f; } v; v.u = ((unsigned)h) << 16;
  return v.f;
}
// async global->LDS, 16B per lane. lds ptr must be wave-uniform; HW writes base + lane*16.
__device__ __forceinline__ void gld16(const void* g, void* l){
  __builtin_amdgcn_global_load_lds((const __attribute__((address_space(1))) unsigned int*)g,
                                   (__attribute__((address_space(3))) unsigned int*)l, 16, 0, 0);
}

// ---------- weight transposes + ln1 in ONE kernel ----------
// blocks 0..4095: Wq/Wk/Wv/Wo; 4096..12287: Wup (G/U interleave); 12288..16383: Wdown;
// blocks 16384..20479: ln1 rows (Hc = LN(Q_in)*g1+b1 + X)
__global__ __launch_bounds__(256) void tr_all(
    const float* __restrict__ Wq, const float* __restrict__ Wk,
    const float* __restrict__ Wv, const float* __restrict__ Wo,
    const float* __restrict__ Wup, const float* __restrict__ Wdown,
    u16* __restrict__ WqkvT, u16* __restrict__ WoT,
    u16* __restrict__ WupT, u16* __restrict__ WdT,
    const float* __restrict__ Qin, const float* __restrict__ X,
    const float* __restrict__ g1, const float* __restrict__ b1,
    u16* __restrict__ HcB)
{
  __shared__ float t[32][33];
  int tx = threadIdx.x, ty = threadIdx.y;
  int id = blockIdx.x;
  if (id >= 16384){
    int row = id - 16384, tid = ty*32 + tx;
    const float4 x = ((const float4*)(Qin + (size_t)row*1024))[tid];
    float s = x.x + x.y + x.z + x.w;
    float sq = x.x*x.x + x.y*x.y + x.z*x.z + x.w*x.w;
    #pragma unroll
    for (int o=32;o>0;o>>=1){ s += __shfl_xor(s, o); sq += __shfl_xor(sq, o); }
    __shared__ float ss[4], ssq[4];
    int wid = tid>>6;
    if ((tid&63)==0){ ss[wid]=s; ssq[wid]=sq; }
    __syncthreads();
    s = ss[0]+ss[1]+ss[2]+ss[3]; sq = ssq[0]+ssq[1]+ssq[2]+ssq[3];
    float mu = s*(1.0f/1024.0f);
    float var = sq*(1.0f/1024.0f) - mu*mu;
    float rstd = rsqrtf(var + 1e-5f);
    float4 xx = ((const float4*)(X + (size_t)row*1024))[tid];
    float4 gv = ((const float4*)g1)[tid];
    float4 bv = ((const float4*)b1)[tid];
    ushort4 o;
    o.x = f2bf((x.x-mu)*rstd*gv.x + bv.x + xx.x);
    o.y = f2bf((x.y-mu)*rstd*gv.y + bv.y + xx.y);
    o.z = f2bf((x.z-mu)*rstd*gv.z + bv.z + xx.z);
    o.w = f2bf((x.w-mu)*rstd*gv.w + bv.w + xx.w);
    ((ushort4*)(HcB + (size_t)row*1024))[tid] = o;
    return;
  }
  if (id < 4096){
    int w = id >> 10, b = id & 1023;
    int c0 = (b & 31)*32, r0 = (b >> 5)*32;
    const float* S = (w==0)?Wq:(w==1)?Wk:(w==2)?Wv:Wo;
    u16* D = (w==3)? WoT : (WqkvT + (size_t)w*1024*1024);
    #pragma unroll
    for (int j=0;j<32;j+=8) t[ty+j][tx] = S[(size_t)(r0+ty+j)*1024 + (c0+tx)];
    __syncthreads();
    #pragma unroll
    for (int j=0;j<32;j+=8) D[(size_t)(c0+ty+j)*1024 + (r0+tx)] = f2bf(t[tx][ty+j]);
  } else if (id < 12288){
    int b = id - 4096;
    int c0 = (b & 255)*32, r0 = (b >> 8)*32;
    #pragma unroll
    for (int j=0;j<32;j+=8) t[ty+j][tx] = Wup[(size_t)(r0+ty+j)*8192 + (c0+tx)];
    __syncthreads();
    #pragma unroll
    for (int j=0;j<32;j+=8){
      int c = c0 + ty + j;
      int rdst = (c < 4096) ? ((c>>4)*32 + (c&15)) : (((c-4096)>>4)*32 + 16 + (c&15));
      WupT[(size_t)rdst*1024 + (r0+tx)] = f2bf(t[tx][ty+j]);
    }
  } else {
    int b = id - 12288;
    int c0 = (b & 31)*32, r0 = (b >> 5)*32;
    #pragma unroll
    for (int j=0;j<32;j+=8) t[ty+j][tx] = Wdown[(size_t)(r0+ty+j)*1024 + (c0+tx)];
    __syncthreads();
    #pragma unroll
    for (int j=0;j<32;j+=8) WdT[(size_t)(c0+ty+j)*4096 + (r0+tx)] = f2bf(t[tx][ty+j]);
  }
}

// ---------- ln2: Qint = Q_in + softplus(dt)*(P0+P1); Qn2 = LN(Qint)*g+b (bf16 partials) ----------
__global__ __launch_bounds__(256) void ln2_kernel(const u16* __restrict__ P,
    const float* __restrict__ Qin, const float* __restrict__ dtp,
    const float* __restrict__ g, const float* __restrict__ b,
    float* __restrict__ Qint, u16* __restrict__ Qn2){
  int row = blockIdx.x, tid = threadIdx.x;
  float sp = log1pf(__expf(dtp[0]));
  size_t off = (size_t)row*1024;
  ushort4 p0 = ((const ushort4*)(P + off))[tid];
  ushort4 p1 = ((const ushort4*)(P + 4194304 + off))[tid];
  float4 q  = ((const float4*)(Qin + off))[tid];
  float4 x;
  x.x = q.x + sp*(bf2f(p0.x)+bf2f(p1.x)); x.y = q.y + sp*(bf2f(p0.y)+bf2f(p1.y));
  x.z = q.z + sp*(bf2f(p0.z)+bf2f(p1.z)); x.w = q.w + sp*(bf2f(p0.w)+bf2f(p1.w));
  ((float4*)(Qint + off))[tid] = x;
  float s = x.x + x.y + x.z + x.w;
  float sq = x.x*x.x + x.y*x.y + x.z*x.z + x.w*x.w;
  #pragma unroll
  for (int o=32;o>0;o>>=1){ s += __shfl_xor(s, o); sq += __shfl_xor(sq, o); }
  __shared__ float ss[4], ssq[4];
  int wid = tid>>6;
  if ((tid&63)==0){ ss[wid]=s; ssq[wid]=sq; }
  __syncthreads();
  s = ss[0]+ss[1]+ss[2]+ss[3]; sq = ssq[0]+ssq[1]+ssq[2]+ssq[3];
  float mu = s*(1.0f/1024.0f);
  float var = sq*(1.0f/1024.0f) - mu*mu;
  float rstd = rsqrtf(var + 1e-5f);
  float4 gv = ((const float4*)g)[tid];
  float4 bv = ((const float4*)b)[tid];
  ushort4 o;
  o.x = f2bf((x.x-mu)*rstd*gv.x + bv.x);
  o.y = f2bf((x.y-mu)*rstd*gv.y + bv.y);
  o.z = f2bf((x.z-mu)*rstd*gv.z + bv.z);
  o.w = f2bf((x.w-mu)*rstd*gv.w + bv.w);
  ((ushort4*)(Qn2 + off))[tid] = o;
}

// ---------- fused QKV GEMM (BK=64), A[4096][1024] @ WqkvT[3072][1024]^T ----------
__global__ __launch_bounds__(256, 3) void gemm_qkv(
    const u16* __restrict__ A, const u16* __restrict__ Bt, void* __restrict__ Op)
{
  __shared__ u16 As[128*64];
  __shared__ u16 Bs[128*64];
  const int tid = threadIdx.x, wid = tid>>6, lane = tid&63;
  const int g = lane>>4, l = lane&15, l7 = l&7;
  const int row0 = blockIdx.x*128, col0 = blockIdx.y*128;
  const int wr = (wid&1)*64, wc = (wid>>1)*64;
  f32x4 acc[4][4] = {};
  for (int k0 = 0; k0 < 1024; k0 += 64){
    __syncthreads();
    #pragma unroll
    for (int i=0;i<4;i++){
      int ch0 = i*256 + wid*64;
      int ch = ch0 + lane;
      int r = ch >> 3, c = ch & 7;
      int cs = c ^ (r & 7);     // 8-phase XOR source swizzle -> conflict-free frag reads
      gld16(A  + (size_t)(row0+r)*1024 + k0 + cs*8, (char*)As + ch0*16);
      gld16(Bt + (size_t)(col0+r)*1024 + k0 + cs*8, (char*)Bs + ch0*16);
    }
    __syncthreads();
    #pragma unroll
    for (int kk=0; kk<2; kk++){
      bf16x8 a[4], b[4];
      #pragma unroll
      for (int i=0;i<4;i++) a[i] = *(const bf16x8*)(As + (wr + i*16 + l)*64 + (((kk*4+g)^l7)*8));
      #pragma unroll
      for (int j=0;j<4;j++) b[j] = *(const bf16x8*)(Bs + (wc + j*16 + l)*64 + (((kk*4+g)^l7)*8));
      #pragma unroll
      for (int i=0;i<4;i++)
        #pragma unroll
        for (int j=0;j<4;j++)
          acc[i][j] = __builtin_amdgcn_mfma_f32_16x16x32_bf16(a[i], b[j], acc[i][j], 0, 0, 0);
    }
  }
  u16* P = (u16*)Op;
  #pragma unroll
  for (int i=0;i<4;i++)
   #pragma unroll
   for (int j=0;j<4;j++){
     int col = col0 + wc + j*16 + l;
     int qk = col >> 10, c = col & 1023;
     int h = c >> 6, d = c & 63;
     int rowb = row0 + wr + i*16 + g*4;
     int bb = rowb >> 11, n = rowb & 2047;
     if (qk == 2){
       ushort4 vs;
       vs.x = f2bf(acc[i][j][0]); vs.y = f2bf(acc[i][j][1]);
       vs.z = f2bf(acc[i][j][2]); vs.w = f2bf(acc[i][j][3]);
       *(ushort4*)(P + (size_t)8388608 + (((size_t)(bb*16 + h))*64 + d)*2048 + n) = vs;
     } else {
       #pragma unroll
       for (int r=0;r<4;r++){
         float v = acc[i][j][r];
         float phi = v > 0.f ? v + 1.f : __expf(v);
         P[(size_t)qk*4194304 + (((size_t)(bb*16 + h))*2048 + (n+r))*64 + d] = f2bf(phi);
       }
     }
   }
}

// ---------- wide-tile GEMM for Wup (BK=64): 256x128 tile, 128x64/wave, fused silu(G)*U ----------
__global__ __launch_bounds__(256, 2) void gemm_wide_up(
    const u16* __restrict__ A, const u16* __restrict__ Bt, u16* __restrict__ Op)
{
  __shared__ u16 As[256*64];   // 32KB
  __shared__ u16 Bs[128*64];   // 16KB
  const int tid = threadIdx.x, wid = tid>>6, lane = tid&63;
  const int g = lane>>4, l = lane&15, l7 = l&7;
  const int bid = blockIdx.x;
  const int bx = bid & 15;
  const int by = (bid>>7)*8 + ((bid>>4) & 7);
  const int row0 = bx*256, col0 = by*128;
  const int wr = (wid&1)*128, wc = (wid>>1)*64;
  f32x4 acc[8][4] = {};
  for (int k0 = 0; k0 < 1024; k0 += 64){
    __syncthreads();
    #pragma unroll
    for (int i=0;i<8;i++){
      int ch0 = i*256 + wid*64;
      int ch = ch0 + lane;
      int r = ch >> 3, c = ch & 7;
      int cs = c ^ (r & 7);
      gld16(A + (size_t)(row0+r)*1024 + k0 + cs*8, (char*)As + ch0*16);
    }
    #pragma unroll
    for (int i=0;i<4;i++){
      int ch0 = i*256 + wid*64;
      int ch = ch0 + lane;
      int r = ch >> 3, c = ch & 7;
      int cs = c ^ (r & 7);
      gld16(Bt + (size_t)(col0+r)*1024 + k0 + cs*8, (char*)Bs + ch0*16);
    }
    __syncthreads();
    #pragma unroll
    for (int kk=0; kk<2; kk++){
      bf16x8 a[8], b[4];
      #pragma unroll
      for (int i=0;i<8;i++) a[i] = *(const bf16x8*)(As + (wr + i*16 + l)*64 + (((kk*4+g)^l7)*8));
      #pragma unroll
      for (int j=0;j<4;j++) b[j] = *(const bf16x8*)(Bs + (wc + j*16 + l)*64 + (((kk*4+g)^l7)*8));
      #pragma unroll
      for (int i=0;i<8;i++)
        #pragma unroll
        for (int j=0;j<4;j++)
          acc[i][j] = __builtin_amdgcn_mfma_f32_16x16x32_bf16(a[i], b[j], acc[i][j], 0, 0, 0);
    }
  }
  #pragma unroll
  for (int i=0;i<8;i++)
   #pragma unroll
   for (int jj=0;jj<4;jj+=2)
    #pragma unroll
    for (int r=0;r<4;r++){
      int row = row0 + wr + i*16 + g*4 + r;
      int pair = (col0 + wc + jj*16) >> 5;
      float G = acc[i][jj][r], U = acc[i][jj+1][r];
      float hf = G/(1.f+__expf(-G))*U;
      Op[(size_t)row*4096 + pair*16 + l] = f2bf(hf);
    }
}

// ---------- split-K GEMM (BK=64): bf16 partial per z-slice ----------
__global__ __launch_bounds__(256, 3) void gemm_part(
    const u16* __restrict__ A, const u16* __restrict__ Bt,
    int Nc, int K, int Ks, u16* __restrict__ Op)
{
  __shared__ u16 As[128*64];
  __shared__ u16 Bs[128*64];
  const int tid = threadIdx.x, wid = tid>>6, lane = tid&63;
  const int g = lane>>4, l = lane&15, l7 = l&7;
  const int row0 = blockIdx.x*128, col0 = blockIdx.y*128;
  const int kbase = blockIdx.z*Ks;
  const int wr = (wid&1)*64, wc = (wid>>1)*64;
  f32x4 acc[4][4] = {};
  for (int k0 = kbase; k0 < kbase + Ks; k0 += 64){
    __syncthreads();
    #pragma unroll
    for (int i=0;i<4;i++){
      int ch0 = i*256 + wid*64;
      int ch = ch0 + lane;
      int r = ch >> 3, c = ch & 7;
      int cs = c ^ (r & 7);
      gld16(A  + (size_t)(row0+r)*K + k0 + cs*8, (char*)As + ch0*16);
      gld16(Bt + (size_t)(col0+r)*K + k0 + cs*8, (char*)Bs + ch0*16);
    }
    __syncthreads();
    #pragma unroll
    for (int kk=0; kk<2; kk++){
      bf16x8 a[4], b[4];
      #pragma unroll
      for (int i=0;i<4;i++) a[i] = *(const bf16x8*)(As + (wr + i*16 + l)*64 + (((kk*4+g)^l7)*8));
      #pragma unroll
      for (int j=0;j<4;j++) b[j] = *(const bf16x8*)(Bs + (wc + j*16 + l)*64 + (((kk*4+g)^l7)*8));
      #pragma unroll
      for (int i=0;i<4;i++)
        #pragma unroll
        for (int j=0;j<4;j++)
          acc[i][j] = __builtin_amdgcn_mfma_f32_16x16x32_bf16(a[i], b[j], acc[i][j], 0, 0, 0);
    }
  }
  u16* P = Op + (size_t)blockIdx.z*4194304;
  #pragma unroll
  for (int i=0;i<4;i++)
   #pragma unroll
   for (int j=0;j<4;j++)
    #pragma unroll
    for (int r=0;r<4;r++){
      int row = row0 + wr + i*16 + g*4 + r;
      int col = col0 + wc + j*16 + l;
      P[(size_t)row*Nc + col] = f2bf(acc[i][j][r]);
    }
}

// ---------- out = Qint + Pd0 + Pd1 (bf16 partials) ----------
__global__ __launch_bounds__(256) void reduce_out(const float* __restrict__ Qint,
    const u16* __restrict__ P, float* __restrict__ out){
  size_t i = (size_t)blockIdx.x*256 + threadIdx.x;
  float4 a  = ((const float4*)Qint)[i];
  ushort4 p0 = ((const ushort4*)P)[i];
  ushort4 p1 = ((const ushort4*)(P + 4194304))[i];
  float4 o;
  o.x = a.x + bf2f(p0.x) + bf2f(p1.x); o.y = a.y + bf2f(p0.y) + bf2f(p1.y);
  o.z = a.z + bf2f(p0.z) + bf2f(p1.z); o.w = a.w + bf2f(p0.w) + bf2f(p1.w);
  ((float4*)out)[i] = o;
}

// ---------- linear attention with relu^2, flash-style ----------
// Q-fragments in registers (loop-invariant). LDS = sK 16 + sV 16 + sW 32 = 64KB -> 2 blocks/CU.
__global__ __launch_bounds__(256, 2) void attn_kernel(
    const u16* __restrict__ PhiQ, const u16* __restrict__ PhiK,
    const u16* __restrict__ Vt, u16* __restrict__ Mb)
{
  __shared__ u16 sK[2][128][32];
  __shared__ u16 sV[4][64][32];
  __shared__ u16 sW[128*128];
  const int tid = threadIdx.x, wid = tid>>6, lane = tid&63;
  const int g = lane>>4, l = lane&15;
  const int l3 = l & 3;
  const int q0 = blockIdx.x*128, bh = blockIdx.y;
  const u16* Q  = PhiQ + (size_t)bh*2048*64;
  const u16* Kb = PhiK + (size_t)bh*2048*64;
  const u16* V  = Vt   + (size_t)bh*64*2048;
  bf16x8 bq[8][2];
  #pragma unroll
  for (int ct=0;ct<8;ct++)
    #pragma unroll
    for (int ks=0;ks<2;ks++)
      bq[ct][ks] = *(const bf16x8*)(Q + (size_t)(q0 + ct*16 + l)*64 + ks*32 + g*8);
  f32x4 accO[2][4] = {};
  float rsum[8] = {0.f,0.f,0.f,0.f,0.f,0.f,0.f,0.f};
  for (int m0 = 0; m0 < 2048; m0 += 128){
    __syncthreads();
    #pragma unroll
    for (int ks=0; ks<2; ks++)
      #pragma unroll
      for (int i=0;i<2;i++){
        int ch0 = i*256 + wid*64;
        int ch = ch0 + lane;
        int r = ch >> 2, q = ch & 3;
        int qs = q ^ (r & 3);
        gld16(Kb + (size_t)(m0+r)*64 + ks*32 + qs*8, (char*)&sK[ks][0][0] + ch0*16);
      }
    #pragma unroll
    for (int c=0; c<4; c++){
      int ch0 = wid*64;
      int ch = ch0 + lane;
      int d = ch >> 2, q = ch & 3;
      int qs = q ^ (d & 3);
      gld16(V + (size_t)d*2048 + m0 + c*32 + qs*8, (char*)&sV[c][0][0] + ch0*16);
    }
    __syncthreads();
    f32x4 st[2][8] = {};
    bf16x8 ak[2][2];
    #pragma unroll
    for (int rt=0;rt<2;rt++)
      #pragma unroll
      for (int ks=0;ks<2;ks++)
        ak[rt][ks] = *(const bf16x8*)&sK[ks][wid*32 + rt*16 + l][(g^l3)*8];
    #pragma unroll
    for (int ct=0;ct<8;ct++){
      #pragma unroll
      for (int ks=0;ks<2;ks++){
        st[0][ct] = __builtin_amdgcn_mfma_f32_16x16x32_bf16(ak[0][ks], bq[ct][ks], st[0][ct], 0,0,0);
        st[1][ct] = __builtin_amdgcn_mfma_f32_16x16x32_bf16(ak[1][ks], bq[ct][ks], st[1][ct], 0,0,0);
      }
    }
    #pragma unroll
    for (int ct=0;ct<8;ct++){
      float part = 0.f;
      #pragma unroll
      for (int rt=0;rt<2;rt++){
        float s0 = fmaxf(st[rt][ct][0], 0.f), s1 = fmaxf(st[rt][ct][1], 0.f);
        float s2 = fmaxf(st[rt][ct][2], 0.f), s3 = fmaxf(st[rt][ct][3], 0.f);
        float w0 = s0*s0, w1 = s1*s1, w2 = s2*s2, w3 = s3*s3;
        part += w0 + w1 + w2 + w3;
        int n = ct*16 + l;
        int mblk = wid*4 + rt*2 + (g>>1);
        ushort4 w4;
        w4.x = f2bf(w0); w4.y = f2bf(w1); w4.z = f2bf(w2); w4.w = f2bf(w3);
        *(ushort4*)(sW + n*128 + ((mblk ^ l)*8) + (g&1)*4) = w4;
      }
      rsum[ct] += part;
    }
    __syncthreads();
    #pragma unroll
    for (int ks=0;ks<4;ks++){
      int n0 = wid*32 + l, n1 = wid*32 + 16 + l;
      bf16x8 aw0 = *(const bf16x8*)(sW + n0*128 + (((ks*4+g) ^ (n0&15))*8));
      bf16x8 aw1 = *(const bf16x8*)(sW + n1*128 + (((ks*4+g) ^ (n1&15))*8));
      #pragma unroll
      for (int ct=0;ct<4;ct++){
        bf16x8 bv = *(const bf16x8*)&sV[ks][ct*16 + l][(g^l3)*8];
        accO[0][ct] = __builtin_amdgcn_mfma_f32_16x16x32_bf16(aw0, bv, accO[0][ct], 0,0,0);
        accO[1][ct] = __builtin_amdgcn_mfma_f32_16x16x32_bf16(aw1, bv, accO[1][ct], 0,0,0);
      }
    }
  }
  __syncthreads();
  float* sRS = (float*)sW;
  float* sNorm = ((float*)sW) + 512;
  #pragma unroll
  for (int ct=0;ct<8;ct++){
    float v = rsum[ct];
    v += __shfl_xor(v, 16);
    v += __shfl_xor(v, 32);
    rsum[ct] = v;
  }
  if (g == 0){
    #pragma unroll
    for (int ct=0;ct<8;ct++) sRS[wid*128 + ct*16 + l] = rsum[ct];
  }
  __syncthreads();
  if (tid < 128) sNorm[tid] = sRS[tid] + sRS[128+tid] + sRS[256+tid] + sRS[384+tid] + 1.0f;
  __syncthreads();
  const int bb = bh >> 4, h = bh & 15;
  #pragma unroll
  for (int rt=0;rt<2;rt++)
   #pragma unroll
   for (int ct=0;ct<4;ct++)
    #pragma unroll
    for (int r=0;r<4;r++){
      int n = wid*32 + rt*16 + g*4 + r;
      int d = ct*16 + l;
      float norm = sNorm[n];
      float vv = bf2f(V[(size_t)d*2048 + q0 + n]);
      float mv = accO[rt][ct][r]/norm - vv;
      Mb[((size_t)(bb*2048) + q0 + n)*1024 + h*64 + d] = f2bf(mv);
    }
}

// ---------- depthwise conv along n (KS=3, pad=1, per batch) ----------
__global__ __launch_bounds__(256) void conv_kernel(const u16* __restrict__ Hf, const float* __restrict__ w,
                                                   u16* __restrict__ Cv){
  int row = blockIdx.y;
  int n = row & 2047;
  int c0 = (blockIdx.x*256 + threadIdx.x)*8;
  us8v h0 = {0,0,0,0,0,0,0,0}, h2 = {0,0,0,0,0,0,0,0};
  us8v h1 = *(const us8v*)(Hf + (size_t)row*4096 + c0);
  if (n > 0)    h0 = *(const us8v*)(Hf + (size_t)(row-1)*4096 + c0);
  if (n < 2047) h2 = *(const us8v*)(Hf + (size_t)(row+1)*4096 + c0);
  us8v o;
  #pragma unroll
  for (int e=0;e<8;e++){
    int c = c0 + e;
    float acc = bf2f(h0[e])*w[c*3+0] + bf2f(h1[e])*w[c*3+1] + bf2f(h2[e])*w[c*3+2];
    o[e] = f2bf(acc);
  }
  *(us8v*)(Cv + (size_t)row*4096 + c0) = o;
}

extern "C" void kernel_launch(void* const* d_in, const int* in_sizes, int n_in,
                              void* d_out, int out_size, void* d_ws, size_t ws_size,
                              hipStream_t stream)
{
  const float* Q_in  = (const float*)d_in[0];
  const float* X     = (const float*)d_in[1];
  const float* Wq    = (const float*)d_in[2];
  const float* Wk    = (const float*)d_in[3];
  const float* Wv    = (const float*)d_in[4];
  const float* Wo    = (const float*)d_in[5];
  const float* Wup   = (const float*)d_in[6];
  const float* convw = (const float*)d_in[7];
  const float* Wdown = (const float*)d_in[8];
  const float* g1    = (const float*)d_in[9];
  const float* b1    = (const float*)d_in[10];
  const float* g2    = (const float*)d_in[11];
  const float* b2    = (const float*)d_in[12];
  const float* dt    = (const float*)d_in[13];
  float* out = (float*)d_out;

  char* ws = (char*)d_ws;
  const size_t MB = (size_t)1 << 20;
  u16* HcB   = (u16*)(ws + 0*MB);     // 8MB  (dead after QKV gemm)
  u16* WqkvT = (u16*)(ws + 8*MB);     // 6MB  (dead after QKV gemm)
  u16* WoT   = (u16*)(ws + 14*MB);    // 2MB  (dead after Wo gemm)
  u16* PhiQ  = (u16*)(ws + 16*MB);    // 8MB  } contiguous: PhiQ,PhiK,Vt (dead after attn)
  u16* Vt    = (u16*)(ws + 32*MB);    // 8MB
  u16* Mb    = (u16*)(ws + 40*MB);    // 8MB  (dead after Wo gemm)
  u16* Po    = (u16*)(ws + 48*MB);    // 16MB 2x bf16 partials (dead after ln2)
  u16* WupT  = (u16*)(ws + 80*MB);    // 16MB
  u16* WdT   = (u16*)(ws + 96*MB);    // 8MB
  float* Qint = (float*)(ws + 104*MB);// 16MB
  u16* Qn2   = (u16*)(ws + 120*MB);   // 8MB  (dead after Wup gemm)
  u16* Hf    = (u16*)(ws + 0*MB);     // 32MB (written after Wup gemm; old region dead)
  u16* Cv    = (u16*)(ws + 40*MB);    // 32MB (over Mb+Po, both dead by conv)
  u16* Pd    = (u16*)(ws + 0*MB);     // 16MB 2x bf16 partials (over Hf, dead after conv)
  u16* PhiK  = PhiQ + 4194304;

  // transposes + ln1 fused
  tr_all<<<20480, dim3(32, 8), 0, stream>>>(Wq, Wk, Wv, Wo, Wup, Wdown,
                                            WqkvT, WoT, WupT, WdT,
                                            Q_in, X, g1, b1, HcB);

  // fused QKV projection: [4096][1024] @ [3072][1024]^T
  gemm_qkv<<<dim3(32, 24), 256, 0, stream>>>(HcB, WqkvT, PhiQ);

  attn_kernel<<<dim3(16, 32), 256, 0, stream>>>(PhiQ, PhiK, Vt, Mb);

  // Wo projection, split-K=2 -> bf16 partials
  gemm_part<<<dim3(32, 8, 2), 256, 0, stream>>>(Mb, WoT, 1024, 1024, 512, Po);

  // Qint = Q_in + softplus(dt)*(Po0+Po1); Qn2 = LN(Qint)
  ln2_kernel<<<4096, 256, 0, stream>>>(Po, Q_in, dt, g2, b2, Qint, Qn2);

  // Wup with fused silu(G)*U epilogue -> Hf [4096][4096], wide 256x128 tiles, BK=64
  gemm_wide_up<<<1024, 256, 0, stream>>>(Qn2, WupT, Hf);

  conv_kernel<<<dim3(2, 4096), 256, 0, stream>>>(Hf, convw, Cv);

  // Wdown split-K=2 -> bf16 partials, then out = Qint + Pd0 + Pd1
  gemm_part<<<dim3(32, 8, 2), 256, 0, stream>>>(Cv, WdT, 1024, 4096, 2048, Pd);
  reduce_out<<<4096, 256, 0, stream>>>(Qint, Pd, out);
}